// Round 2
// baseline (706.583 us; speedup 1.0000x reference)
//
#include <hip/hip_runtime.h>

// 2-layer LSTM, B=512, T=1024, H=64 (tf LSTMCell, gates i,j,f,o, forget bias 1.0)
// TWO batch elements per block (grid 256 = 1 block/CU), 640 thr = 10 waves.
//   Waves 0-7 (compute): wave w owns gate columns [32w,32w+32) for BOTH
//   elements; gate g = w>>1. W1 weights in registers are SHARED across the two
//   elements (33 floats/thread, split-k halves as before), so the matvec FMA
//   streams for e0/e1 interleave -> ILP covers the latency that TLP covered
//   when 2 independent blocks shared a CU, while barrier + LDS round-trip
//   costs are amortized over 2 elements.
//   SPLIT-K: lanes 0-31 = W1 rows 0..32 (incl x-row+bias), lanes 32-63 rows
//   33..64; halves combined IN-REGISTER via v_permlane32_swap (no LDS trip).
//   gs layout [elem][par][gate][unit]: half h writes element h's activation ->
//   2 lanes/bank distinct-addr (free); reads are stride-1 b32 (conflict-free).
//   Cell update for both elements replicated in all 8 waves (benign
//   same-value writes; each wave writes & reads the full h1s itself).
//   Waves 8/9: full layer-2 recurrence for element 0/1, one step behind.

#define TT 1024

__device__ __forceinline__ float fsig(float x) {
    return __builtin_amdgcn_rcpf(1.f + __expf(-x));
}
__device__ __forceinline__ float ftanh(float x) {
    return 1.f - 2.f * __builtin_amdgcn_rcpf(1.f + __expf(2.f * x));
}

template <int Ctrl, int Rmask>
__device__ __forceinline__ float dpp_add(float x) {
    int t = __builtin_amdgcn_update_dpp(0, __float_as_int(x), Ctrl, Rmask, 0xf, true);
    return x + __int_as_float(t);
}
// Sum across 64 lanes; result valid in lane 63. 6 dependent VALU ops.
__device__ __forceinline__ float wave_sum64(float x) {
    x = dpp_add<0x111, 0xf>(x); // row_shr:1
    x = dpp_add<0x112, 0xf>(x); // row_shr:2
    x = dpp_add<0x114, 0xf>(x); // row_shr:4
    x = dpp_add<0x118, 0xf>(x); // row_shr:8
    x = dpp_add<0x142, 0xa>(x); // row_bcast:15
    x = dpp_add<0x143, 0xc>(x); // row_bcast:31 ; lane63 = total
    return x;
}

// p + p[lane^32] in every lane, pure VALU (no LDS round-trip).
// permlane32_swap returns both updated words; their sum is the cross-half sum
// in all 64 lanes regardless of output-order convention.
#if __has_builtin(__builtin_amdgcn_permlane32_swap)
__device__ __forceinline__ float halfsum(float p) {
    auto r = __builtin_amdgcn_permlane32_swap(__float_as_uint(p), __float_as_uint(p),
                                              false, false);
    return __uint_as_float(r[0]) + __uint_as_float(r[1]);
}
#else
__device__ __forceinline__ float halfsum(float p) { return p + __shfl_xor(p, 32); }
#endif

__global__ __launch_bounds__(640, 1) void lstm2_kernel(
    const float* __restrict__ x,    // [B, T]
    const float* __restrict__ W1,   // [65, 256]; row0 = x, rows 1..64 = h1
    const float* __restrict__ b1,   // [256]
    const float* __restrict__ W2,   // [65, 4]; rows 0..63 = h1, row 64 = h2
    const float* __restrict__ b2,   // [4]
    float* __restrict__ y)          // [B, T]
{
    __shared__ __align__(16) float xs[2][TT];        // x rows, both elements
    __shared__ __align__(16) float h1s[2][2][64];    // [elem][parity][unit]
    __shared__ __align__(16) float gs[2][2][4][64];  // [elem][parity][gate][unit]

    const int tid  = threadIdx.x;
    const int b0   = blockIdx.x * 2;
    const int lane = tid & 63;
    const int cw   = tid >> 6;        // 0..7 compute, 8/9 layer-2 (elem 0/1)
    const int half = lane >> 5;       // split-k half within the wave
    const int l31  = lane & 31;

    // stage both x rows into LDS (coalesced float4)
    if (tid < 512) {
        const int e = tid >> 8, i = tid & 255;
        ((float4*)xs[e])[i] = ((const float4*)(x + (size_t)(b0 + e) * TT))[i];
    }
    if (tid < 256) ((float*)h1s)[tid] = 0.f;   // all parity buffers, both elems

    if (cw < 8) {
        // ---------------- compute waves ----------------
        const int col   = (cw << 5) | l31;         // gate column
        const int g     = cw >> 1;                 // gate id (wave-uniform)
        const int gunit = ((cw & 1) << 5) | l31;   // hidden unit this col feeds

        // per-thread layer-1 weights: 33 floats (half a column), shared by
        // both batch elements
        float w[33];
        float bias = 0.f;
        if (half == 0) {
            w[0] = W1[col];
            bias = b1[col];
#pragma unroll
            for (int j = 1; j <= 32; ++j) w[j] = W1[j * 256 + col];         // rows 1..32
        } else {
            w[0] = 0.f;                            // no x term, no bias upper half
#pragma unroll
            for (int j = 1; j <= 32; ++j) w[j] = W1[(32 + j) * 256 + col];  // rows 33..64
        }

        // unified activation constants (wave-uniform, branch-free):
        //   act = aa + bb * rcp(1 + exp2(mm*p + kk))
        //   i,o: sigmoid(p); f: sigmoid(p+1); j: tanh(p)
        const float L2E = 1.4426950408889634f;
        const float mm = (g == 1) ? 2.f * L2E : -L2E;
        const float kk = (g == 2) ? -L2E : 0.f;
        const float aa = (g == 1) ? 1.f : 0.f;
        const float bb = (g == 1) ? -2.f : 1.f;

        const int hrow = half << 3;   // float4 base index into a 64-float h1 row
        float c1a = 0.f, c1b = 0.f;   // cell state of unit `lane`, elems 0/1
        __syncthreads();              // barrier #1 (xs/h1s staged)

        // One step for BOTH elements; PAR is compile-time so all LDS
        // addressing is base + immediate.
#define STEP(PAR, XT0, XT1) { \
        float a00 = fmaf((XT0), w[0], bias), a01 = 0.f, a02 = 0.f, a03 = 0.f; \
        float a10 = fmaf((XT1), w[0], bias), a11 = 0.f, a12 = 0.f, a13 = 0.f; \
        const float4* hb0 = (const float4*)(&h1s[0][(PAR) ^ 1][0]); \
        const float4* hb1 = (const float4*)(&h1s[1][(PAR) ^ 1][0]); \
        _Pragma("unroll") \
        for (int q = 0; q < 8; ++q) { \
            float4 u0 = hb0[hrow + q]; \
            float4 u1 = hb1[hrow + q]; \
            a00 = fmaf(u0.x, w[1 + 4 * q], a00); \
            a01 = fmaf(u0.y, w[2 + 4 * q], a01); \
            a02 = fmaf(u0.z, w[3 + 4 * q], a02); \
            a03 = fmaf(u0.w, w[4 + 4 * q], a03); \
            a10 = fmaf(u1.x, w[1 + 4 * q], a10); \
            a11 = fmaf(u1.y, w[2 + 4 * q], a11); \
            a12 = fmaf(u1.z, w[3 + 4 * q], a12); \
            a13 = fmaf(u1.w, w[4 + 4 * q], a13); \
        } \
        float p0 = halfsum((a00 + a01) + (a02 + a03)); \
        float p1 = halfsum((a10 + a11) + (a12 + a13)); \
        float act0 = fmaf(bb, __builtin_amdgcn_rcpf(1.f + exp2f(fmaf(mm, p0, kk))), aa); \
        float act1 = fmaf(bb, __builtin_amdgcn_rcpf(1.f + exp2f(fmaf(mm, p1, kk))), aa); \
        gs[half][PAR][g][gunit] = half ? act1 : act0; \
        __syncthreads(); \
        { \
            float i0 = gs[0][PAR][0][lane], j0 = gs[0][PAR][1][lane]; \
            float f0 = gs[0][PAR][2][lane], o0 = gs[0][PAR][3][lane]; \
            float i1 = gs[1][PAR][0][lane], j1 = gs[1][PAR][1][lane]; \
            float f1 = gs[1][PAR][2][lane], o1 = gs[1][PAR][3][lane]; \
            c1a = fmaf(c1a, f0, i0 * j0); \
            c1b = fmaf(c1b, f1, i1 * j1); \
            float r0 = __builtin_amdgcn_rcpf(1.f + exp2f(c1a * (2.f * 1.4426950408889634f))); \
            float r1 = __builtin_amdgcn_rcpf(1.f + exp2f(c1b * (2.f * 1.4426950408889634f))); \
            h1s[0][PAR][lane] = fmaf(-2.f, r0 * o0, o0); \
            h1s[1][PAR][lane] = fmaf(-2.f, r1 * o1, o1); \
        } }

        for (int t = 0; t < TT; t += 4) {
            float4 xa = *(const float4*)(xs[0] + t);
            float4 xb = *(const float4*)(xs[1] + t);
            STEP(0, xa.x, xb.x)
            STEP(1, xa.y, xb.y)
            STEP(0, xa.z, xb.z)
            STEP(1, xa.w, xb.w)
        }
#undef STEP
        __syncthreads();              // tail barrier (publish h1(TT-1))
    } else {
        // ------------- waves 8/9: layer 2 for element e, one step behind -------------
        const int e = cw & 1;
        float4 w2g4 = *(const float4*)(W2 + lane * 4);   // W2[lane][0..3]
        const float w2h0 = W2[256], w2h1 = W2[257], w2h2 = W2[258], w2h3 = W2[259];
        const float b20 = b2[0], b21 = b2[1], b22 = b2[2], b23 = b2[3];
        float c2 = 0.f, h2 = 0.f;     // state lives in lane 63
        float* yrow = y + (size_t)(b0 + e) * TT;
        __syncthreads();              // barrier #1

        for (int t = 0; t < TT; ++t) {
            __syncthreads();          // rendezvous with compute mid-step barrier
            if (t > 0) {
                const float hv = h1s[e][(t - 1) & 1][lane];   // h1(t-1)
                const float d0 = wave_sum64(hv * w2g4.x);
                const float d1 = wave_sum64(hv * w2g4.y);
                const float d2 = wave_sum64(hv * w2g4.z);
                const float d3 = wave_sum64(hv * w2g4.w);
                if (lane == 63) {
                    const float i2 = fsig (fmaf(h2, w2h0, d0) + b20);
                    const float j2 = ftanh(fmaf(h2, w2h1, d1) + b21);
                    const float f2 = fsig (fmaf(h2, w2h2, d2) + b22 + 1.f);
                    const float o2 = fsig (fmaf(h2, w2h3, d3) + b23);
                    c2 = fmaf(c2, f2, i2 * j2);
                    h2 = ftanh(c2) * o2;
                    yrow[t - 1] = h2;
                }
            }
        }
        __syncthreads();              // matches compute tail barrier
        {   // final step (t = TT-1)
            const float hv = h1s[e][(TT - 1) & 1][lane];
            const float d0 = wave_sum64(hv * w2g4.x);
            const float d1 = wave_sum64(hv * w2g4.y);
            const float d2 = wave_sum64(hv * w2g4.z);
            const float d3 = wave_sum64(hv * w2g4.w);
            if (lane == 63) {
                const float i2 = fsig (fmaf(h2, w2h0, d0) + b20);
                const float j2 = ftanh(fmaf(h2, w2h1, d1) + b21);
                const float f2 = fsig (fmaf(h2, w2h2, d2) + b22 + 1.f);
                const float o2 = fsig (fmaf(h2, w2h3, d3) + b23);
                c2 = fmaf(c2, f2, i2 * j2);
                h2 = ftanh(c2) * o2;
                yrow[TT - 1] = h2;
            }
        }
    }
}

extern "C" void kernel_launch(void* const* d_in, const int* in_sizes, int n_in,
                              void* d_out, int out_size, void* d_ws, size_t ws_size,
                              hipStream_t stream) {
    const float* x  = (const float*)d_in[0];
    const float* W1 = (const float*)d_in[1];
    const float* b1 = (const float*)d_in[2];
    const float* W2 = (const float*)d_in[3];
    const float* b2 = (const float*)d_in[4];
    float* y = (float*)d_out;
    lstm2_kernel<<<256, 640, 0, stream>>>(x, W1, b1, W2, b2, y);
}